// Round 8
// baseline (107.536 us; speedup 1.0000x reference)
//
#include <hip/hip_runtime.h>

#define NVV   778
#define NSEG  16
#define SEGSZ 49
#define GRIDN 32
#define BATCH 128
#define NPTS  (NSEG * SEGSZ)           // 784
#define VOLSZ (GRIDN * GRIDN * GRIDN)  // 32768 floats = 128 KB
#define NVOL  (2 * BATCH * NSEG)       // 4096
#define NBLK  256
#define VPB   (NVOL / NBLK)            // 16 volumes per persistent block

// 3-piece z-split, 12 slabs (48 KB) each, ring-buffered:
//   piece 0: slabs  0..11  serves z0 in [-1,10]
//   piece 1: slabs 11..22  serves z0 in [11,21]
//   piece 2: slabs 20..31  serves z0 in [22,31]
#define PF      (12 * 1024)            // floats per piece (48 KB)

typedef __attribute__((address_space(1))) const void* as1_t;
typedef __attribute__((address_space(3))) void* as3_t;

// 48 chunks of 1 KB; each of 16 waves issues exactly 3 global_load_lds.
// Counted-vmcnt correctness depends on "3 DMA per wave per phase, issued
// last in the phase" — keep this macro fenced at both ends.
#define STREAM(DST, SRC) \
    { _Pragma("unroll") \
      for (int c_ = 0; c_ < 3; ++c_) { \
        int ch_ = c_ * 16 + wv; \
        __builtin_amdgcn_global_load_lds( \
            (as1_t)((SRC) + ch_ * 256 + lane * 4), \
            (as3_t)((DST) + ch_ * 256), 16, 0, 0); \
      } }

#define FENCE asm volatile("" ::: "memory")

// counted wait + raw barrier: allow this phase's N DMA loads to remain in
// flight; everything older is retired. lgkmcnt(0) flushes ds_writes (wsum/
// sbox) for cross-wave visibility, matching __syncthreads semantics.
#define WAITB(N) \
    { asm volatile("s_waitcnt vmcnt(" #N ") lgkmcnt(0)" ::: "memory"); \
      __builtin_amdgcn_s_barrier(); }

#define PV_LOAD(IT, nx, ny, nz) \
    if ((IT) < VPB && tid < NPTS) { \
        int vid_ = bx + NBLK * (IT); \
        int b_   = (vid_ >> 4) & (BATCH - 1); \
        int src_ = (vid_ >> 11) == 0 ? 1 : 0; \
        const float* v_ = vertices + (((size_t)b_ * 2 + src_) * NVV + pvi) * 3; \
        nx = v_[0]; ny = v_[1]; nz = v_[2]; \
    }

// 2x2x2 taps within one resident piece. zrel0 = z0 - piece_base_slab.
__device__ __forceinline__ float taps_piece(
    const float* base, int zrel0, bool z0ok, bool z1ok,
    int x0, int y0, float wx, float wy, float wz)
{
    float s = 0.f;
    #pragma unroll
    for (int dz = 0; dz < 2; ++dz) {
        if (!(dz ? z1ok : z0ok)) continue;
        float wwz = dz ? wz : 1.f - wz;
        const float* slab = base + (zrel0 + dz) * (GRIDN * GRIDN);
        #pragma unroll
        for (int dy = 0; dy < 2; ++dy) {
            int yy = y0 + dy;
            if (yy < 0 || yy >= GRIDN) continue;
            float wzy = wwz * (dy ? wy : 1.f - wy);
            const float* row = slab + yy * GRIDN;
            #pragma unroll
            for (int dx = 0; dx < 2; ++dx) {
                int xx = x0 + dx;
                if (xx < 0 || xx >= GRIDN) continue;
                s += wzy * (dx ? wx : 1.f - wx) * row[xx];
            }
        }
    }
    return s;
}

// Persistent: 256 blocks x 1024 threads (1/CU, ~148 KB LDS). 3-buffer ring
// with counted vmcnt waits: piece tapped in phase P was streamed in P-2 and
// covered by P-1's wait, while P's own 48 KB stream stays in flight across
// the barrier — the HBM queue never drains in the main loop.
__global__ __launch_bounds__(1024, 4) void sample_kernel(
    const float* __restrict__ vertices, const int* __restrict__ seg,
    const float* __restrict__ phiR, const float* __restrict__ phiL,
    float* __restrict__ loss)
{
    __shared__ __align__(16) float B0[PF];
    __shared__ __align__(16) float B1[PF];
    __shared__ __align__(16) float B2[PF];
    __shared__ float4 sbox[VPB];
    __shared__ float wsum[16];

    const int tid  = threadIdx.x;
    const int bx   = blockIdx.x;
    const int k    = bx & (NSEG - 1);    // constant per block (256 % 16 == 0)
    const int wv   = tid >> 6;
    const int lane = tid & 63;

    auto phiPtr = [&](int it) {
        int vid  = bx + NBLK * it;
        int b    = (vid >> 4) & (BATCH - 1);
        int pass = vid >> 11;            // NSEG*BATCH = 2048
        return (pass == 0 ? phiR : phiL) + ((size_t)k * BATCH + b) * VOLSZ;
    };

    // ---- prologue: all scattered vmem FIRST (so DMAs are newest) ----
    int pvi = (tid < NPTS) ? seg[tid] : 0;

    // box inputs (wave wv handles volume wv's box)
    int vidw  = bx + NBLK * wv;
    int bbw   = (vidw >> 4) & (BATCH - 1);
    int boxSide = ((vidw >> 11) == 0) ? 0 : 1;   // opposite of sampled side
    bool bact = lane < SEGSZ;
    int bvi = bact ? seg[k * SEGSZ + lane] : 0;
    const float* bv = vertices + (((size_t)bbw * 2 + boxSide) * NVV + bvi) * 3;
    float bxx = bv[0], bxy = bv[1], bxz = bv[2];

    float pvx = 0.f, pvy = 0.f, pvz = 0.f;
    float nvx = 0.f, nvy = 0.f, nvz = 0.f;
    PV_LOAD(0, pvx, pvy, pvz)

    FENCE;
    {
        const float* p0 = phiPtr(0);
        STREAM(B0, p0)                   // piece 0 of volume 0
        STREAM(B1, p0 + 11 * 1024)       // piece 1 of volume 0
    }
    FENCE;

    // box shfl-reduce (register-only; compiler waits the box loads here)
    {
        float mnx = bact ? bxx : 1e30f, mxx = bact ? bxx : -1e30f;
        float mny = bact ? bxy : 1e30f, mxy = bact ? bxy : -1e30f;
        float mnz = bact ? bxz : 1e30f, mxz = bact ? bxz : -1e30f;
        #pragma unroll
        for (int m = 32; m; m >>= 1) {
            mnx = fminf(mnx, __shfl_xor(mnx, m));
            mxx = fmaxf(mxx, __shfl_xor(mxx, m));
            mny = fminf(mny, __shfl_xor(mny, m));
            mxy = fmaxf(mxy, __shfl_xor(mxy, m));
            mnz = fminf(mnz, __shfl_xor(mnz, m));
            mxz = fmaxf(mxz, __shfl_xor(mxz, m));
        }
        if (lane == 0) {
            float ext = fmaxf(fmaxf(mxx - mnx, mxy - mny), mxz - mnz);
            sbox[wv] = make_float4(0.5f * (mnx + mxx), 0.5f * (mny + mxy),
                                   0.5f * (mnz + mxz), 1.0f / (0.55f * ext));
        }
    }

    WAITB(3)   // B0 complete; B1's 3 loads may stay in flight

    for (int v = 0; v < VPB; ++v) {
        const float* pc_phi = phiPtr(v);
        const bool more = (v + 1 < VPB);

        // per-volume point setup (sbox resident since prologue barrier)
        float fx = 0.f, fy = 0.f, fz = -2.f;
        if (tid < NPTS) {
            float4 b4 = sbox[v];
            fx = ((pvx - b4.x) * b4.w + 1.f) * 15.5f;
            fy = ((pvy - b4.y) * b4.w + 1.f) * 15.5f;
            fz = ((pvz - b4.z) * b4.w + 1.f) * 15.5f;
        }
        bool active = (fx > -1.f && fx < 32.f && fy > -1.f && fy < 32.f &&
                       fz > -1.f && fz < 32.f);
        float x0f = floorf(fx), y0f = floorf(fy), z0f = floorf(fz);
        float wx = fx - x0f, wy = fy - y0f, wz = fz - z0f;
        int x0 = (int)x0f, y0 = (int)y0f, z0 = (int)z0f;
        int pc = (z0 <= 10) ? 0 : ((z0 <= 21) ? 1 : 2);
        float acc = 0.f;

        // ---- phase q0: stream piece 3v+2 -> B2; tap piece 3v from B0 ----
        PV_LOAD(v + 1, nvx, nvy, nvz)
        FENCE;
        STREAM(B2, pc_phi + 20 * 1024)
        FENCE;
        if (active && pc == 0)
            acc += taps_piece(B0, z0, z0 >= 0, true, x0, y0, wx, wy, wz);
        WAITB(3)

        // ---- phase q1: stream piece 3(v+1) -> B0; tap from B1 ----
        if (more) {
            const float* pn = phiPtr(v + 1);
            FENCE;
            STREAM(B0, pn)
            FENCE;
        }
        if (active && pc == 1)
            acc += taps_piece(B1, z0 - 11, true, true, x0, y0, wx, wy, wz);
        if (more) { WAITB(3) } else { WAITB(0) }

        // ---- phase q2: stream piece 3(v+1)+1 -> B1; tap from B2 ----
        if (more) {
            const float* pn = phiPtr(v + 1);
            FENCE;
            STREAM(B1, pn + 11 * 1024)
            FENCE;
        }
        if (active && pc == 2)
            acc += taps_piece(B2, z0 - 20, true, z0 < 31, x0, y0, wx, wy, wz);

        // per-volume reduction
        #pragma unroll
        for (int off = 32; off; off >>= 1)
            acc += __shfl_down(acc, off);
        if (lane == 0) wsum[wv] = acc;
        if (more) { WAITB(3) } else { WAITB(0) }
        if (tid == 0) {
            float tot = 0.f;
            #pragma unroll
            for (int i = 0; i < 16; ++i) tot += wsum[i];
            int vid = bx + NBLK * v;
            atomicAdd(loss + ((vid >> 4) & (BATCH - 1)), tot * 0.25f);
        }
        pvx = nvx; pvy = nvy; pvz = nvz;
    }
}

extern "C" void kernel_launch(void* const* d_in, const int* in_sizes, int n_in,
                              void* d_out, int out_size, void* d_ws, size_t ws_size,
                              hipStream_t stream) {
    const float* vertices = (const float*)d_in[0];
    const float* phiR     = (const float*)d_in[1];
    const float* phiL     = (const float*)d_in[2];
    const int*   seg      = (const int*)d_in[3];
    float* loss = (float*)d_out;

    hipMemsetAsync(d_out, 0, (size_t)out_size * sizeof(float), stream);

    sample_kernel<<<NBLK, 1024, 0, stream>>>(vertices, seg, phiR, phiL, loss);
}